// Round 1
// baseline (494.841 us; speedup 1.0000x reference)
//
#include <hip/hip_runtime.h>
#include <hip/hip_bf16.h>

#define Bv 32
#define Nv 4096
#define Dv 64
#define Hv 64
#define Fv 128
#define Ev 65536
#define Sv 2
#define Ov 128
#define Mv 5

using short8  = __attribute__((ext_vector_type(8))) short;
using floatx4 = __attribute__((ext_vector_type(4))) float;

__device__ __forceinline__ float bflo(unsigned u){ unsigned v = u << 16; float f; __builtin_memcpy(&f, &v, 4); return f; }
__device__ __forceinline__ float bfhi(unsigned u){ unsigned v = u & 0xffff0000u; float f; __builtin_memcpy(&f, &v, 4); return f; }
__device__ __forceinline__ unsigned short f2bf(float f){
  unsigned x; __builtin_memcpy(&x, &f, 4);
  x += 0x7fffu + ((x >> 16) & 1u);           // RNE
  return (unsigned short)(x >> 16);
}
__device__ __forceinline__ unsigned bfpack(float a, float b){
  return (unsigned)f2bf(a) | ((unsigned)f2bf(b) << 16);
}

// ---------------- CSR build ----------------
__global__ void k_zero(int* __restrict__ p, int n){
  int i = blockIdx.x * 256 + threadIdx.x;
  if(i < n) p[i] = 0;
}

__global__ void k_hist(const int* __restrict__ rows, int* __restrict__ deg){
  int i = blockIdx.x * 256 + threadIdx.x;           // [0, S*E)
  int s = i >> 16;                                  // E = 65536
  int r = rows[i];
  atomicAdd(&deg[s * Nv + r], 1);
}

__global__ void k_scan(const int* __restrict__ deg, int* __restrict__ rowptr, int* __restrict__ cursor){
  __shared__ int part[256];
  __shared__ int sbase[256];
  int t = threadIdx.x;
  for(int s = 0; s < Sv; s++){
    int loc[16]; int sum = 0;
    #pragma unroll
    for(int i = 0; i < 16; i++){ loc[i] = deg[s * Nv + t * 16 + i]; sum += loc[i]; }
    part[t] = sum;
    __syncthreads();
    if(t == 0){ int run = 0; for(int i = 0; i < 256; i++){ int v = part[i]; sbase[i] = run; run += v; } }
    __syncthreads();
    int run = sbase[t];
    #pragma unroll
    for(int i = 0; i < 16; i++){
      int idx = t * 16 + i;
      rowptr[s * (Nv + 1) + idx] = run;
      cursor[s * Nv + idx] = run;
      run += loc[i];
    }
    if(t == 255) rowptr[s * (Nv + 1) + Nv] = run;
    __syncthreads();
  }
}

__global__ void k_scatter(const int* __restrict__ rows, const int* __restrict__ cols,
                          const float* __restrict__ vals, int* __restrict__ cursor,
                          int* __restrict__ colsrt, float* __restrict__ valsrt){
  int i = blockIdx.x * 256 + threadIdx.x;           // [0, S*E)
  int s = i >> 16;
  int r = rows[i];
  int p = atomicAdd(&cursor[s * Nv + r], 1);
  colsrt[(s << 16) + p] = cols[i];
  valsrt[(s << 16) + p] = vals[i];
}

// ---------------- build X0 (bf16, layout [b][n][f]) ----------------
__global__ void k_buildx0(const float* __restrict__ inp, const float* __restrict__ st,
                          unsigned* __restrict__ X0u){
  int t = blockIdx.x * 256 + threadIdx.x;           // [0, B*N*64) -- one bf16x2 per thread
  int f2 = t & 63;
  int n  = (t >> 6) & (Nv - 1);
  int b  = t >> 18;
  float2 v;
  if(f2 < 32) v = *(const float2*)(inp + (size_t)b * Nv * Dv + n * Dv + f2 * 2);
  else        v = *(const float2*)(st  + (size_t)b * Nv * Hv + n * Hv + (f2 - 32) * 2);
  X0u[(size_t)(b * Nv + n) * 64 + f2] = bfpack(v.x, v.y);
}

// ---------------- weights: Wb[m][o][f] bf16 (transposed for gemm_bt) ----------------
__global__ void k_wb(const float* __restrict__ wg, unsigned short* __restrict__ Wb){
  int t = blockIdx.x * 256 + threadIdx.x;           // [0, M*O*F)
  if(t >= Mv * Ov * Fv) return;
  int f = t & (Fv - 1);
  int o = (t >> 7) & (Ov - 1);
  int m = t >> 14;
  Wb[t] = f2bf(wg[(f * Mv + m) * Ov + o]);
}

// ---------------- SpMM: one wave per (row r, group of 4 b) ----------------
// step1: dst = A_s * src   (xprev == nullptr)
// step2: dst = 2 * A_s * src - xprev
__launch_bounds__(256)
__global__ void k_spmm(const unsigned* __restrict__ src0, const unsigned* __restrict__ src1,
                       unsigned* __restrict__ dst0, unsigned* __restrict__ dst1,
                       const unsigned* __restrict__ xprev,
                       const int* __restrict__ rowptr, const int* __restrict__ colsrt,
                       const float* __restrict__ valsrt){
  const int lane = threadIdx.x & 63;
  const int wv   = threadIdx.x >> 6;
  const int bid  = blockIdx.x;                      // 0..16383
  const int s    = bid >> 13;
  const int gw   = ((bid & 8191) << 2) | wv;        // 0..32767
  const int r    = gw >> 3;
  const int bg   = (gw & 7) << 2;                   // b = bg..bg+3
  const unsigned* __restrict__ src = s ? src1 : src0;
  unsigned* __restrict__ dst       = s ? dst1 : dst0;
  const int j0 = rowptr[s * (Nv + 1) + r];
  const int j1 = rowptr[s * (Nv + 1) + r + 1];
  const int* __restrict__ cs   = colsrt + (s << 16);
  const float* __restrict__ vs = valsrt + (s << 16);
  const unsigned* __restrict__ sb0 = src + (size_t)(bg + 0) * (Nv * 64);
  const unsigned* __restrict__ sb1 = src + (size_t)(bg + 1) * (Nv * 64);
  const unsigned* __restrict__ sb2 = src + (size_t)(bg + 2) * (Nv * 64);
  const unsigned* __restrict__ sb3 = src + (size_t)(bg + 3) * (Nv * 64);

  float a00 = 0.f, a01 = 0.f, a10 = 0.f, a11 = 0.f;
  float a20 = 0.f, a21 = 0.f, a30 = 0.f, a31 = 0.f;
  for(int j = j0; j < j1; j++){
    const int off = cs[j] * 64 + lane;
    const float v = vs[j];
    const unsigned x0 = sb0[off];
    const unsigned x1 = sb1[off];
    const unsigned x2 = sb2[off];
    const unsigned x3 = sb3[off];
    a00 += v * bflo(x0); a01 += v * bfhi(x0);
    a10 += v * bflo(x1); a11 += v * bfhi(x1);
    a20 += v * bflo(x2); a21 += v * bfhi(x2);
    a30 += v * bflo(x3); a31 += v * bfhi(x3);
  }
  const int roff = r * 64 + lane;
  if(xprev){
    const unsigned p0 = xprev[(size_t)(bg + 0) * (Nv * 64) + roff];
    const unsigned p1 = xprev[(size_t)(bg + 1) * (Nv * 64) + roff];
    const unsigned p2 = xprev[(size_t)(bg + 2) * (Nv * 64) + roff];
    const unsigned p3 = xprev[(size_t)(bg + 3) * (Nv * 64) + roff];
    a00 = 2.f * a00 - bflo(p0); a01 = 2.f * a01 - bfhi(p0);
    a10 = 2.f * a10 - bflo(p1); a11 = 2.f * a11 - bfhi(p1);
    a20 = 2.f * a20 - bflo(p2); a21 = 2.f * a21 - bfhi(p2);
    a30 = 2.f * a30 - bflo(p3); a31 = 2.f * a31 - bfhi(p3);
  }
  dst[(size_t)(bg + 0) * (Nv * 64) + roff] = bfpack(a00, a01);
  dst[(size_t)(bg + 1) * (Nv * 64) + roff] = bfpack(a10, a11);
  dst[(size_t)(bg + 2) * (Nv * 64) + roff] = bfpack(a20, a21);
  dst[(size_t)(bg + 3) * (Nv * 64) + roff] = bfpack(a30, a31);
}

// ---------------- GEMM: out[r][o] = sum_m A_m[r][:] . Wb[m][o][:] + bias[o] ----------------
// A_m row-major [131072, 128] bf16; Wb[m] row-major [128 (o), 128 (f)] bf16 (pre-transposed).
__launch_bounds__(256)
__global__ void k_gemm(const unsigned short* __restrict__ X0,
                       const unsigned short* __restrict__ X1a,
                       const unsigned short* __restrict__ X2a,
                       const unsigned short* __restrict__ X1b,
                       const unsigned short* __restrict__ X2b,
                       const unsigned short* __restrict__ Wb,
                       const float* __restrict__ bias,
                       float* __restrict__ out){
  __shared__ unsigned short Asm[128 * 32];
  __shared__ unsigned short Bsm[128 * 32];
  const unsigned short* Am[5] = {X0, X1a, X2a, X1b, X2b};
  const int tid  = threadIdx.x;
  const int lane = tid & 63, wv = tid >> 6;
  const int wm = wv >> 1, wn = wv & 1;
  const int lrow = lane & 15, quad = lane >> 4;
  const size_t r0 = (size_t)blockIdx.x * 128;

  floatx4 acc[4][4] = {};

  #pragma unroll
  for(int m = 0; m < 5; m++){
    const unsigned short* Ab = Am[m] + r0 * Fv;
    const unsigned short* Bb = Wb + m * (Ov * Fv);
    #pragma unroll
    for(int kk = 0; kk < Fv; kk += 32){
      __syncthreads();
      #pragma unroll
      for(int p = 0; p < 2; p++){
        int idx = p * 256 + tid;
        int row = idx >> 2, seg = idx & 3;
        *(uint4*)(&Asm[row * 32 + seg * 8]) = *(const uint4*)(Ab + (size_t)row * Fv + kk + seg * 8);
        *(uint4*)(&Bsm[row * 32 + seg * 8]) = *(const uint4*)(Bb + row * Fv + kk + seg * 8);
      }
      __syncthreads();
      short8 af[4], bfr[4];
      #pragma unroll
      for(int t = 0; t < 4; t++){
        af[t]  = *(const short8*)(&Asm[(wm * 64 + t * 16 + lrow) * 32 + quad * 8]);
        bfr[t] = *(const short8*)(&Bsm[(wn * 64 + t * 16 + lrow) * 32 + quad * 8]);
      }
      #pragma unroll
      for(int ti = 0; ti < 4; ti++)
        #pragma unroll
        for(int tj = 0; tj < 4; tj++)
          acc[ti][tj] = __builtin_amdgcn_mfma_f32_16x16x32_bf16(af[ti], bfr[tj], acc[ti][tj], 0, 0, 0);
    }
  }

  #pragma unroll
  for(int ti = 0; ti < 4; ti++){
    #pragma unroll
    for(int tj = 0; tj < 4; tj++){
      const int col = wn * 64 + tj * 16 + lrow;
      const float bv = bias[col];
      const size_t rbase = r0 + wm * 64 + ti * 16 + quad * 4;
      #pragma unroll
      for(int t = 0; t < 4; t++){
        out[(rbase + t) * Ov + col] = acc[ti][tj][t] + bv;
      }
    }
  }
}

extern "C" void kernel_launch(void* const* d_in, const int* in_sizes, int n_in,
                              void* d_out, int out_size, void* d_ws, size_t ws_size,
                              hipStream_t stream) {
  (void)in_sizes; (void)n_in; (void)out_size; (void)ws_size;
  const float* inp  = (const float*)d_in[0];
  const float* st   = (const float*)d_in[1];
  const int*   rows = (const int*)d_in[2];
  const int*   cols = (const int*)d_in[3];
  const float* vals = (const float*)d_in[4];
  const float* wght = (const float*)d_in[5];
  const float* bias = (const float*)d_in[6];
  float* out = (float*)d_out;

  char* w = (char*)d_ws;
  const size_t SZX = (size_t)Bv * Nv * Fv * 2;      // 32 MiB per bf16 matrix
  unsigned short* X0  = (unsigned short*)(w);
  unsigned short* X1a = (unsigned short*)(w + SZX);
  unsigned short* X2a = (unsigned short*)(w + 2 * SZX);
  unsigned short* X1b = (unsigned short*)(w + 3 * SZX);
  unsigned short* X2b = (unsigned short*)(w + 4 * SZX);
  unsigned short* Wb  = (unsigned short*)(w + 5 * SZX);     // 160 KiB used, 256 KiB reserved
  char* p2 = w + 5 * SZX + 262144;
  int* deg    = (int*)p2;                       // [S*N]
  int* cursor = deg + Sv * Nv;                  // [S*N]
  int* rowptr = cursor + Sv * Nv;               // [S*(N+1)]
  int* colsrt = rowptr + Sv * (Nv + 1) + 62;    // pad to alignment; [S*E]
  float* valsrt = (float*)(colsrt + Sv * Ev);   // [S*E]
  // total ws use: 5*32MiB + ~1.5 MiB  (~162 MiB)

  k_zero<<<(Sv * Nv + 255) / 256, 256, 0, stream>>>(deg, Sv * Nv);
  k_hist<<<Sv * Ev / 256, 256, 0, stream>>>(rows, deg);
  k_scan<<<1, 256, 0, stream>>>(deg, rowptr, cursor);
  k_scatter<<<Sv * Ev / 256, 256, 0, stream>>>(rows, cols, vals, cursor, colsrt, valsrt);
  k_buildx0<<<(Bv * Nv * 64) / 256, 256, 0, stream>>>(inp, st, (unsigned*)X0);
  k_wb<<<(Mv * Ov * Fv + 255) / 256, 256, 0, stream>>>(wght, Wb);

  // x1 = A_s x0 for both supports
  k_spmm<<<16384, 256, 0, stream>>>((const unsigned*)X0, (const unsigned*)X0,
                                    (unsigned*)X1a, (unsigned*)X1b,
                                    (const unsigned*)nullptr, rowptr, colsrt, valsrt);
  // x2 = 2 A_s x1 - x0 for both supports
  k_spmm<<<16384, 256, 0, stream>>>((const unsigned*)X1a, (const unsigned*)X1b,
                                    (unsigned*)X2a, (unsigned*)X2b,
                                    (const unsigned*)X0, rowptr, colsrt, valsrt);

  k_gemm<<<(Bv * Nv) / 128, 256, 0, stream>>>(X0, X1a, X2a, X1b, X2b, Wb, bias, out);
}